// Round 5
// baseline (384.417 us; speedup 1.0000x reference)
//
#include <hip/hip_runtime.h>

typedef unsigned short u16;
typedef __bf16 bf16x8 __attribute__((ext_vector_type(8)));
typedef float f32x4 __attribute__((ext_vector_type(4)));

// ---------- sizes ----------
#define Bsz 8192
#define Fdim 1024
#define Udim 512
#define Odim 3
#define Adim 6
#define Hdim 4

// ws element offsets (u16 elements)
#define OFF_FEAT   0
#define OFF_WAL    8388608     // W_lat = [W_al ; W_ol] contiguous (2048 x 1024)
#define OFF_WOL    8912896
#define OFF_WIN    10485760
#define OFF_WOUT   11272192
#define OFF_WAH    11534336
#define OFF_WOH    12058624
#define OFF_LAT    12845056    // B x 2048 : [agent_latent | opp0 | opp1 | opp2]

// d_out offsets (fp32 elements)
#define OUT_AP 0
#define OUT_AV 49152
#define OUT_OP 57344
#define OUT_OV 204800
#define OUT_IN 229376

__device__ __forceinline__ u16 f2bf(float f) {
  return __builtin_bit_cast(u16, (__bf16)f);
}
__device__ __forceinline__ float bf2f(u16 u) {
  return (float)__builtin_bit_cast(__bf16, u);
}

__device__ __forceinline__ void gload16(const u16* g, u16* s) {
  __builtin_amdgcn_global_load_lds(
      (const __attribute__((address_space(1))) unsigned int*)g,
      (__attribute__((address_space(3))) unsigned int*)s, 16, 0, 0);
}

// ---------- fp32 -> bf16 conversion of features + all GEMM weights ----------
#define CV_E0 2097152
#define CV_E1 2228224
#define CV_E2 2621440
#define CV_E3 2818048
#define CV_E4 2883584
#define CV_E5 3014656
#define CV_E6 3211264
__global__ __launch_bounds__(256) void convert_all(
    const float* __restrict__ f, const float* __restrict__ wal,
    const float* __restrict__ wol, const float* __restrict__ win,
    const float* __restrict__ wout, const float* __restrict__ wah,
    const float* __restrict__ woh, u16* __restrict__ dst) {
  int i = blockIdx.x * 256 + threadIdx.x;
  if (i >= CV_E6) return;
  const float* src;
  int base;
  if (i < CV_E0)      { src = f;    base = 0; }
  else if (i < CV_E1) { src = wal;  base = CV_E0; }
  else if (i < CV_E2) { src = wol;  base = CV_E1; }
  else if (i < CV_E3) { src = win;  base = CV_E2; }
  else if (i < CV_E4) { src = wout; base = CV_E3; }
  else if (i < CV_E5) { src = wah;  base = CV_E4; }
  else                { src = woh;  base = CV_E5; }
  float4 v = ((const float4*)src)[i - base];
  ushort4 o;
  o.x = f2bf(v.x); o.y = f2bf(v.y); o.z = f2bf(v.z); o.w = f2bf(v.w);
  ((ushort4*)dst)[i] = o;
}

// ============================================================================
// 256x256 8-phase bf16 GEMM for lat = elu(feat @ W_lat^T + b). Unchanged from
// round 2 (verified: FETCH near-ideal, 0 bank conflicts).
// ============================================================================
#define BAR() __builtin_amdgcn_s_barrier()
#define FENCE() asm volatile("" ::: "memory")
#define LGKM0() asm volatile("s_waitcnt lgkmcnt(0)" ::: "memory")
#define VMW(n) asm volatile("s_waitcnt vmcnt(" #n ")" ::: "memory")
#define MFMA(a, b, c) __builtin_amdgcn_mfma_f32_16x16x32_bf16(a, b, c, 0, 0, 0)
#define STAGE(MAT, SRC, LD, buf, ks, kb) do {                    \
    const u16* _s = (SRC) + (size_t)(kb) + (ks) * 32;            \
    gload16(_s, &MAT[buf][ks][wave * 512]);                      \
    gload16(_s + (size_t)128 * (LD), &MAT[buf][ks][4096 + wave * 512]); \
  } while (0)
#define RD_A(cur, ks, mh) do {                                   \
    _Pragma("unroll")                                            \
    for (int mi = 0; mi < 4; mi++)                               \
      a0[mi] = *(const bf16x8*)&As[cur][ks][aoff + (mh)*2048 + mi*512]; \
  } while (0)
#define RD_B(cur, ks) do {                                       \
    _Pragma("unroll")                                            \
    for (int ni = 0; ni < 4; ni++)                               \
      b0[ni] = *(const bf16x8*)&Bs[cur][ks][boff + ni*512];      \
  } while (0)
#define MFMA8(mh) do {                                           \
    __builtin_amdgcn_s_setprio(1);                               \
    _Pragma("unroll")                                            \
    for (int mi = 0; mi < 4; mi++) {                             \
      _Pragma("unroll")                                          \
      for (int ni = 0; ni < 4; ni++)                             \
        acc[(mh)*4+mi][ni] = MFMA(a0[mi], b0[ni], acc[(mh)*4+mi][ni]); \
    }                                                            \
    __builtin_amdgcn_s_setprio(0);                               \
  } while (0)

template <bool ELU>
__global__ __launch_bounds__(512, 2) void gemm256(
    const u16* __restrict__ A, const u16* __restrict__ Bw, u16* __restrict__ C,
    const float* __restrict__ bias1, const float* __restrict__ bias2,
    int bsplit, int K, int lda, int ldb, int ldc,
    long sAz, long sBz, long sCz, int sbz, float scale) {
  __shared__ __align__(16) u16 As[2][2][8192];
  __shared__ __align__(16) u16 Bs[2][2][8192];
  const int tid = threadIdx.x;
  const int wave = tid >> 6, lane = tid & 63;
  const int wr = wave >> 2, wc = wave & 3;

  const int nx = gridDim.x, ny = gridDim.y;
  const int nxy = nx * ny;
  const int nwg = nxy * gridDim.z;
  const int orig = blockIdx.x + nx * (blockIdx.y + ny * blockIdx.z);
  const int xcd = orig & 7;
  const int qd = nwg >> 3, rd = nwg & 7;
  const int wg = (xcd < rd ? xcd * (qd + 1) : rd * (qd + 1) + (xcd - rd) * qd)
               + (orig >> 3);
  const int z = wg / nxy;
  const int rem = wg - z * nxy;
  const int by = rem / nx;
  const int bx = rem - by * nx;

  A += (size_t)z * sAz;
  Bw += (size_t)z * sBz;
  C += (size_t)z * sCz;
  bias1 += (size_t)z * sbz;

  const int tM = by * 256, tN = bx * 256;

  const int srow = tid >> 2;
  const int schunk = ((tid & 3) ^ ((tid >> 3) & 3)) * 8;
  const u16* Asrc = A + (size_t)(tM + srow) * lda + schunk;
  const u16* Bsrc = Bw + (size_t)(tN + srow) * ldb + schunk;

  const int laneLo = lane & 15;
  const int pc8 = (((lane >> 4) ^ ((lane >> 1) & 3))) * 8;
  const int aoff = (wr * 128 + laneLo) * 32 + pc8;
  const int boff = (wc * 64 + laneLo) * 32 + pc8;

  f32x4 acc[8][4];
#pragma unroll
  for (int mi = 0; mi < 8; mi++)
#pragma unroll
    for (int ni = 0; ni < 4; ni++) acc[mi][ni] = (f32x4){0.f, 0.f, 0.f, 0.f};

  const int NT = K >> 6;

  STAGE(As, Asrc, lda, 0, 0, 0);
  STAGE(Bs, Bsrc, ldb, 0, 0, 0);
  STAGE(As, Asrc, lda, 0, 1, 0);
  STAGE(Bs, Bsrc, ldb, 0, 1, 0);
  VMW(4);
  BAR();

  int cur = 0;
  int kb = 64;
  bf16x8 a0[4], b0[4];
  for (int t = 0; t < NT; ++t) {
    const int nxt = cur ^ 1;
    const bool st = (t + 1 < NT);
    RD_B(cur, 0);
    RD_A(cur, 0, 0);
    if (st) STAGE(As, Asrc, lda, nxt, 0, kb);
    FENCE(); BAR(); LGKM0();
    MFMA8(0);
    FENCE(); BAR();
    RD_A(cur, 0, 1);
    if (st) STAGE(Bs, Bsrc, ldb, nxt, 0, kb);
    FENCE(); BAR(); LGKM0();
    MFMA8(1);
    if (st) { VMW(4); } else { VMW(0); }
    BAR();
    RD_B(cur, 1);
    RD_A(cur, 1, 0);
    if (st) STAGE(As, Asrc, lda, nxt, 1, kb);
    FENCE(); BAR(); LGKM0();
    MFMA8(0);
    FENCE(); BAR();
    RD_A(cur, 1, 1);
    if (st) STAGE(Bs, Bsrc, ldb, nxt, 1, kb);
    FENCE(); BAR(); LGKM0();
    MFMA8(1);
    if (st) { VMW(4); BAR(); }
    cur = nxt;
    kb += 64;
  }

#pragma unroll
  for (int ni = 0; ni < 4; ni++) {
    const int col = tN + wc * 64 + ni * 16 + laneLo;
    const float bv = (col < bsplit) ? bias1[col] : bias2[col - bsplit];
#pragma unroll
    for (int gm = 0; gm < 8; gm++) {
      const int row0 = tM + wr * 128 + gm * 16 + (lane >> 4) * 4;
#pragma unroll
      for (int r = 0; r < 4; r++) {
        float v = (acc[gm][ni][r] + bv) * scale;
        if (ELU) v = v > 0.f ? v : (__expf(v) - 1.f);
        C[(size_t)(row0 + r) * ldc + col] = f2bf(v);
      }
    }
  }
}
#undef STAGE
#undef RD_A
#undef RD_B
#undef MFMA8

// ============================================================================
// brain: fused q/k/v + attention + attn_out + agent_head + opp_heads + all
// output heads. One block = 32 batch rows, 512 threads = 8 waves; wave w owns
// output cols w*64..w*64+63 of every row-local GEMM (N=512).
// Structure identical to round 3 (agent path harness-verified); single fix:
// DOTS for opponent o now receives W_op + o*3072 / W_ov + o*512 (the weight
// pointers were missing the per-opponent offset; bias already had it).
// ============================================================================
#define GEMM16(ACC, BG, LDB, ABUF, AKB, BKB) do {                              \
    _Pragma("unroll 4")                                                        \
    for (int k_ = 0; k_ < 16; ++k_) {                                          \
      bf16x8 af0_ = *(const bf16x8*)&(ABUF)[ll*512 + ((((AKB)+k_)*4+lh)^l7)*8];\
      bf16x8 af1_ = *(const bf16x8*)&(ABUF)[(16+ll)*512 + ((((AKB)+k_)*4+lh)^l7)*8]; \
      _Pragma("unroll")                                                        \
      for (int nf_ = 0; nf_ < 4; ++nf_) {                                      \
        bf16x8 bf_ = *(const bf16x8*)((BG) + (size_t)(wc0 + nf_*16 + ll)*(LDB) \
                                      + ((BKB)+k_)*32 + lh*8);                 \
        ACC[0][nf_] = MFMA(af0_, bf_, ACC[0][nf_]);                            \
        ACC[1][nf_] = MFMA(af1_, bf_, ACC[1][nf_]);                            \
      }                                                                        \
    }                                                                          \
  } while (0)

#define ZACC(ACC) do {                                                         \
    _Pragma("unroll")                                                          \
    for (int mf_ = 0; mf_ < 2; ++mf_)                                          \
      _Pragma("unroll")                                                        \
      for (int nf_ = 0; nf_ < 4; ++nf_)                                        \
        ACC[mf_][nf_] = (f32x4){0.f, 0.f, 0.f, 0.f};                           \
  } while (0)

#define STAGE_OL0(CB) do {                                                     \
    _Pragma("unroll")                                                          \
    for (int j_ = 0; j_ < 4; ++j_) {                                           \
      int gq_ = j_*512 + tid;                                                  \
      int r_ = gq_ >> 6, s_ = gq_ & 63, c_ = s_ ^ (r_ & 7);                    \
      gload16(lat + (size_t)(row0 + r_)*2048 + (CB) + c_*8,                    \
              &OL[0][j_*4096 + wave*512]);                                     \
    }                                                                          \
  } while (0)

// 28 length-512 dots: kq=lane&7 owns a 64-elem slice, 8 rows/wave, waves 0..3.
#define DOTS(BUF, WPp, BPp, WVp, BVp, AGENT, OO) do {                          \
    if (wave < 4) {                                                            \
      const int rl_ = wave*8 + (lane >> 3), kq_ = lane & 7;                    \
      const int b_ = row0 + rl_;                                               \
      bf16x8 av_[8];                                                           \
      _Pragma("unroll")                                                        \
      for (int c_ = 0; c_ < 8; ++c_)                                           \
        av_[c_] = *(const bf16x8*)&(BUF)[rl_*512 + c_*64 + kq_*8];             \
      _Pragma("unroll")                                                        \
      for (int p_ = 0; p_ < 7; ++p_) {                                         \
        const float* wg_ = (p_ < 6) ? (WPp) + p_*512 : (WVp);                  \
        float ac_ = 0.f;                                                       \
        _Pragma("unroll")                                                      \
        for (int c_ = 0; c_ < 8; ++c_) {                                       \
          float4 w0_ = *(const float4*)(wg_ + c_*64 + kq_*8);                  \
          float4 w1_ = *(const float4*)(wg_ + c_*64 + kq_*8 + 4);              \
          ac_ += (float)av_[c_][0]*w0_.x + (float)av_[c_][1]*w0_.y             \
               + (float)av_[c_][2]*w0_.z + (float)av_[c_][3]*w0_.w             \
               + (float)av_[c_][4]*w1_.x + (float)av_[c_][5]*w1_.y             \
               + (float)av_[c_][6]*w1_.z + (float)av_[c_][7]*w1_.w;            \
        }                                                                      \
        ac_ += __shfl_xor(ac_, 1, 64);                                         \
        ac_ += __shfl_xor(ac_, 2, 64);                                         \
        ac_ += __shfl_xor(ac_, 4, 64);                                         \
        if (kq_ == p_) {                                                       \
          if (AGENT) {                                                         \
            if (p_ < 6) out[OUT_AP + b_*6 + p_] = ac_ + (BPp)[p_];             \
            else        out[OUT_AV + b_] = ac_ + (BVp)[0];                     \
          } else {                                                             \
            if (p_ < 6) out[OUT_OP + b_*18 + (OO)*6 + p_] = ac_ + (BPp)[(OO)*6 + p_]; \
            else        out[OUT_OV + b_*3 + (OO)] = ac_ + (BVp)[(OO)];         \
          }                                                                    \
        }                                                                      \
      }                                                                        \
    }                                                                          \
  } while (0)

__global__ __launch_bounds__(512) void brain(
    const u16* __restrict__ lat, const u16* __restrict__ win,
    const u16* __restrict__ wout, const u16* __restrict__ wah,
    const u16* __restrict__ woh,
    const float* __restrict__ b_in, const float* __restrict__ b_out,
    const float* __restrict__ b_ah, const float* __restrict__ b_oh,
    const float* __restrict__ Wap, const float* __restrict__ bap,
    const float* __restrict__ Wav, const float* __restrict__ bav,
    const float* __restrict__ Wop, const float* __restrict__ bop,
    const float* __restrict__ Wov, const float* __restrict__ bov,
    float* __restrict__ out) {
  __shared__ __align__(16) u16 AL[16384];
  __shared__ __align__(16) u16 OL[3][16384];
  __shared__ float sc_s[2][384];   // [wave parity][row*12 + h*3 + o]
  __shared__ float wt_s[384];

  const int tid = threadIdx.x;
  const int wave = tid >> 6, lane = tid & 63;
  const int ll = lane & 15, lh = lane >> 4, l7 = lane & 7;
  const int wc0 = wave * 64;
  const int h3 = (wave >> 1) * 3;  // head index * 3 (2 waves per 128-col head)
  const int wp = wave & 1;
  const int row0 = blockIdx.x * 32;

  // ---- stage al + all three opp latents (swizzled), zero score buffer ----
#pragma unroll
  for (int j_ = 0; j_ < 4; ++j_) {
    int gq_ = j_*512 + tid;
    int r_ = gq_ >> 6, s_ = gq_ & 63, c_ = s_ ^ (r_ & 7);
    const u16* src_ = lat + (size_t)(row0 + r_) * 2048 + c_ * 8;
    gload16(src_,        &AL[j_*4096 + wave*512]);
    gload16(src_ + 512,  &OL[0][j_*4096 + wave*512]);
    gload16(src_ + 1024, &OL[1][j_*4096 + wave*512]);
    gload16(src_ + 1536, &OL[2][j_*4096 + wave*512]);
  }
  for (int i = tid; i < 768; i += 512) ((float*)sc_s)[i] = 0.f;
  __syncthreads();

  // ---- q = (al @ Wq^T + bq) * scale : stays in registers ----
  f32x4 qacc[2][4];
  ZACC(qacc);
  GEMM16(qacc, win, 512, AL, 0, 0);
#pragma unroll
  for (int nf = 0; nf < 4; ++nf) {
    float bq_ = b_in[wc0 + nf*16 + ll];
#pragma unroll
    for (int mf = 0; mf < 2; ++mf)
#pragma unroll
      for (int rr = 0; rr < 4; ++rr)
        qacc[mf][nf][rr] = (qacc[mf][nf][rr] + bq_) * 0.08838834764831845f;
  }

  // ---- scores: k_o = ol_o @ Wk^T (+bk), dot with q in-register ----
  float bkv[4];
#pragma unroll
  for (int nf = 0; nf < 4; ++nf) bkv[nf] = b_in[512 + wc0 + nf*16 + ll];
  for (int o = 0; o < 3; ++o) {
    f32x4 kacc[2][4];
    ZACC(kacc);
    GEMM16(kacc, win + 262144, 512, OL[o], 0, 0);
    float part0[4] = {0.f, 0.f, 0.f, 0.f}, part1[4] = {0.f, 0.f, 0.f, 0.f};
#pragma unroll
    for (int nf = 0; nf < 4; ++nf)
#pragma unroll
      for (int rr = 0; rr < 4; ++rr) {
        part0[rr] += qacc[0][nf][rr] * (kacc[0][nf][rr] + bkv[nf]);
        part1[rr] += qacc[1][nf][rr] * (kacc[1][nf][rr] + bkv[nf]);
      }
#pragma unroll
    for (int rr = 0; rr < 4; ++rr) {
      float p0 = part0[rr], p1 = part1[rr];
      p0 += __shfl_xor(p0, 1, 64); p1 += __shfl_xor(p1, 1, 64);
      p0 += __shfl_xor(p0, 2, 64); p1 += __shfl_xor(p1, 2, 64);
      p0 += __shfl_xor(p0, 4, 64); p1 += __shfl_xor(p1, 4, 64);
      p0 += __shfl_xor(p0, 8, 64); p1 += __shfl_xor(p1, 8, 64);
      if (ll == 0) {
        sc_s[wp][(lh*4 + rr)*12 + h3 + o] = p0;
        sc_s[wp][(16 + lh*4 + rr)*12 + h3 + o] = p1;
      }
    }
  }
  __syncthreads();

  // ---- softmax over O=3 per (row, head) ----
  if (tid < 128) {
    int r = tid >> 2, h = tid & 3;
    int i = r*12 + h*3;
    float s0 = sc_s[0][i+0] + sc_s[1][i+0];
    float s1 = sc_s[0][i+1] + sc_s[1][i+1];
    float s2 = sc_s[0][i+2] + sc_s[1][i+2];
    float m = fmaxf(s0, fmaxf(s1, s2));
    float e0 = __expf(s0 - m), e1 = __expf(s1 - m), e2 = __expf(s2 - m);
    float inv = 1.f / (e0 + e1 + e2);
    wt_s[i+0] = e0 * inv; wt_s[i+1] = e1 * inv; wt_s[i+2] = e2 * inv;
  }
  __syncthreads();

  // ---- influences ----
  if (tid < 96) {
    int r = tid / 3, o = tid - r * 3;
    out[OUT_IN + (size_t)(row0 + r)*3 + o] =
        (wt_s[r*12 + o] + wt_s[r*12 + 3 + o] + wt_s[r*12 + 6 + o] +
         wt_s[r*12 + 9 + o]) * 0.25f;
  }

  // ---- att = sum_o w[row,h,o] * (ol_o @ Wv^T + bv) : folded in registers ----
  float bvv[4];
#pragma unroll
  for (int nf = 0; nf < 4; ++nf) bvv[nf] = b_in[1024 + wc0 + nf*16 + ll];
  f32x4 att[2][4];
  ZACC(att);
  for (int o = 0; o < 3; ++o) {
    f32x4 vacc[2][4];
    ZACC(vacc);
    GEMM16(vacc, win + 524288, 512, OL[o], 0, 0);
#pragma unroll
    for (int mf = 0; mf < 2; ++mf)
#pragma unroll
      for (int rr = 0; rr < 4; ++rr) {
        float wv = wt_s[(mf*16 + lh*4 + rr)*12 + h3 + o];
#pragma unroll
        for (int nf = 0; nf < 4; ++nf)
          att[mf][nf][rr] += wv * (vacc[mf][nf][rr] + bvv[nf]);
      }
  }
  // store att (bf16, swizzled) -> OL[1]
#pragma unroll
  for (int mf = 0; mf < 2; ++mf)
#pragma unroll
    for (int nf = 0; nf < 4; ++nf)
#pragma unroll
      for (int rr = 0; rr < 4; ++rr) {
        int row = mf*16 + lh*4 + rr;
        int col = wc0 + nf*16 + ll;
        OL[1][row*512 + (((col >> 3) ^ (row & 7))*8) + (col & 7)] =
            f2bf(att[mf][nf][rr]);
      }
  __syncthreads();

  // ---- aout = att @ Wout^T + b_out -> OL[2] (swizzled) ----
  {
    f32x4 ao[2][4];
    ZACC(ao);
    GEMM16(ao, wout, 512, OL[1], 0, 0);
#pragma unroll
    for (int nf = 0; nf < 4; ++nf) {
      float bb = b_out[wc0 + nf*16 + ll];
#pragma unroll
      for (int mf = 0; mf < 2; ++mf)
#pragma unroll
        for (int rr = 0; rr < 4; ++rr) {
          int row = mf*16 + lh*4 + rr;
          int col = wc0 + nf*16 + ll;
          OL[2][row*512 + (((col >> 3) ^ (row & 7))*8) + (col & 7)] =
              f2bf(ao[mf][nf][rr] + bb);
        }
    }
  }
  __syncthreads();

  // ---- agh = elu([al | aout] @ Wah^T + b_ah) -> OL[1] (linear) ----
  {
    f32x4 gh[2][4];
    ZACC(gh);
    GEMM16(gh, wah, 1024, AL, 0, 0);
    GEMM16(gh, wah, 1024, OL[2], 0, 16);
#pragma unroll
    for (int nf = 0; nf < 4; ++nf) {
      float bb = b_ah[wc0 + nf*16 + ll];
#pragma unroll
      for (int mf = 0; mf < 2; ++mf)
#pragma unroll
        for (int rr = 0; rr < 4; ++rr) {
          int row = mf*16 + lh*4 + rr;
          int col = wc0 + nf*16 + ll;
          float v = gh[mf][nf][rr] + bb;
          v = v > 0.f ? v : (__expf(v) - 1.f);
          OL[1][row*512 + col] = f2bf(v);
        }
    }
  }
  __syncthreads();

  // ---- agent policy/value heads ----
  DOTS(OL[1], Wap, bap, Wav, bav, 1, 0);

  // ---- opp heads: oph_o = elu(ol_o @ Woh_o^T + b_oh_o), then dots ----
  for (int o = 0; o < 3; ++o) {
    if (o > 0) {               // ol_o was overwritten; reload into OL[0]
      STAGE_OL0(512 * (1 + o));
      __syncthreads();
    }
    const int dst = (o == 1) ? 1 : 2;      // o=0->OL[2], o=1->OL[1], o=2->OL[2]
    f32x4 oh[2][4];
    ZACC(oh);
    GEMM16(oh, woh + (size_t)o * 262144, 512, OL[0], 0, 0);
#pragma unroll
    for (int nf = 0; nf < 4; ++nf) {
      float bb = b_oh[o*512 + wc0 + nf*16 + ll];
#pragma unroll
      for (int mf = 0; mf < 2; ++mf)
#pragma unroll
        for (int rr = 0; rr < 4; ++rr) {
          int row = mf*16 + lh*4 + rr;
          int col = wc0 + nf*16 + ll;
          float v = oh[mf][nf][rr] + bb;
          v = v > 0.f ? v : (__expf(v) - 1.f);
          OL[dst][row*512 + col] = f2bf(v);
        }
    }
    __syncthreads();
    // FIX: weight pointers need the per-opponent offset (bias already indexed
    // by OO inside DOTS; weights were reading opponent 0's matrices).
    DOTS(OL[dst], Wop + (size_t)o * 3072, bop, Wov + (size_t)o * 512, bov, 0, o);
  }
}

extern "C" void kernel_launch(void* const* d_in, const int* in_sizes, int n_in,
                              void* d_out, int out_size, void* d_ws, size_t ws_size,
                              hipStream_t stream) {
  (void)in_sizes; (void)n_in; (void)out_size; (void)ws_size;
  const float* f     = (const float*)d_in[0];
  const float* W_al  = (const float*)d_in[1];
  const float* b_al  = (const float*)d_in[2];
  const float* W_in  = (const float*)d_in[3];
  const float* b_in  = (const float*)d_in[4];
  const float* W_out = (const float*)d_in[5];
  const float* b_out = (const float*)d_in[6];
  const float* W_ah  = (const float*)d_in[7];
  const float* b_ah  = (const float*)d_in[8];
  const float* W_ap  = (const float*)d_in[9];
  const float* b_ap  = (const float*)d_in[10];
  const float* W_av  = (const float*)d_in[11];
  const float* b_av  = (const float*)d_in[12];
  const float* W_ol  = (const float*)d_in[13];
  const float* b_ol  = (const float*)d_in[14];
  const float* W_oh  = (const float*)d_in[15];
  const float* b_oh  = (const float*)d_in[16];
  const float* W_op  = (const float*)d_in[17];
  const float* b_op  = (const float*)d_in[18];
  const float* W_ov  = (const float*)d_in[19];
  const float* b_ov  = (const float*)d_in[20];
  float* out = (float*)d_out;
  u16* ws = (u16*)d_ws;

  u16* feat = ws + OFF_FEAT;
  u16* wal  = ws + OFF_WAL;   // [W_al ; W_ol] = W_lat (2048 x 1024)
  u16* win  = ws + OFF_WIN;
  u16* wout = ws + OFF_WOUT;
  u16* wah  = ws + OFF_WAH;
  u16* woh  = ws + OFF_WOH;
  u16* lat  = ws + OFF_LAT;   // B x 2048

  convert_all<<<12544, 256, 0, stream>>>(f, W_al, W_ol, W_in, W_out, W_ah,
                                         W_oh, ws);

  // lat = elu(feat @ W_lat^T + [b_al|b_ol]) : B x 2048
  gemm256<true><<<dim3(8, 32, 1), 512, 0, stream>>>(
      feat, wal, lat, b_al, b_ol, 512, 1024, 1024, 1024, 2048, 0, 0, 0, 0, 1.f);

  // everything else: one fused row-local kernel
  brain<<<256, 512, 0, stream>>>(lat, win, wout, wah, woh,
                                 b_in, b_out, b_ah, b_oh,
                                 W_ap, b_ap, W_av, b_av,
                                 W_op, b_op, W_ov, b_ov, out);
}